// Round 1
// baseline (795.828 us; speedup 1.0000x reference)
//
#include <hip/hip_runtime.h>

namespace {

constexpr float kScale = 0.17677669529663687f;  // 32^-0.5

// ---------------- qkv GEMM: C[r][j] = sum_k x[r][k]*w[j][k] + b[j] ----------
// M=32768, N=768, K=256. 64x64 tile, BK=32, 4x4 micro-tile.
__global__ __launch_bounds__(256) void qkv_gemm_kernel(
    const float* __restrict__ x, const float* __restrict__ w,
    const float* __restrict__ bias, float* __restrict__ q,
    float* __restrict__ kk, float* __restrict__ v) {
  __shared__ __align__(16) float As[32][68];
  __shared__ __align__(16) float Bs[32][68];
  const int tid = threadIdx.x;
  const int row0 = blockIdx.y * 64;
  const int col0 = blockIdx.x * 64;
  const int tx = tid & 15, ty = tid >> 4;
  float acc[4][4] = {};
  for (int k0 = 0; k0 < 256; k0 += 32) {
#pragma unroll
    for (int i = 0; i < 2; ++i) {
      const int s = tid + i * 256;
      const int r = s >> 3, k4 = s & 7;
      const float4 a4 = *reinterpret_cast<const float4*>(
          &x[(size_t)(row0 + r) * 256 + k0 + k4 * 4]);
      As[k4 * 4 + 0][r] = a4.x; As[k4 * 4 + 1][r] = a4.y;
      As[k4 * 4 + 2][r] = a4.z; As[k4 * 4 + 3][r] = a4.w;
      const float4 b4 = *reinterpret_cast<const float4*>(
          &w[(size_t)(col0 + r) * 256 + k0 + k4 * 4]);
      Bs[k4 * 4 + 0][r] = b4.x; Bs[k4 * 4 + 1][r] = b4.y;
      Bs[k4 * 4 + 2][r] = b4.z; Bs[k4 * 4 + 3][r] = b4.w;
    }
    __syncthreads();
#pragma unroll
    for (int p = 0; p < 32; ++p) {
      const float4 av = *reinterpret_cast<const float4*>(&As[p][ty * 4]);
      const float4 bv = *reinterpret_cast<const float4*>(&Bs[p][tx * 4]);
      const float aa[4] = {av.x, av.y, av.z, av.w};
      const float bb[4] = {bv.x, bv.y, bv.z, bv.w};
#pragma unroll
      for (int i = 0; i < 4; ++i)
#pragma unroll
        for (int j = 0; j < 4; ++j) acc[i][j] = fmaf(aa[i], bb[j], acc[i][j]);
    }
    __syncthreads();
  }
  // epilogue: col -> (t, h, c); scatter to q/k/v [b][h][n][c]
  const int col = col0 + tx * 4;
  const int tsel = col >> 8;
  const int hh = (col >> 5) & 7;
  const int cc = col & 31;
  float* dst = (tsel == 0) ? q : (tsel == 1) ? kk : v;
  const float4 bias4 = *reinterpret_cast<const float4*>(&bias[col]);
#pragma unroll
  for (int i = 0; i < 4; ++i) {
    const int r = row0 + ty * 4 + i;
    const int bb_ = r >> 12, n = r & 4095;
    float4 o;
    o.x = acc[i][0] + bias4.x; o.y = acc[i][1] + bias4.y;
    o.z = acc[i][2] + bias4.z; o.w = acc[i][3] + bias4.w;
    *reinterpret_cast<float4*>(
        &dst[((size_t)(bb_ * 8 + hh) * 4096 + n) * 32 + cc]) = o;
  }
}

// -------------- k column-max partials (softmax over N per (b,h,c)) ---------
__global__ __launch_bounds__(256) void kmax_kernel(const float* __restrict__ k,
                                                   float* __restrict__ part) {
  const int bh = blockIdx.x;     // 0..63
  const int chunk = blockIdx.y;  // 0..7 (512 rows each)
  const int t = threadIdx.x;
  const float* kb = k + (size_t)bh * 131072 + (size_t)chunk * 512 * 32;
  float m = -3.4e38f;
  for (int i = t; i < 512 * 32; i += 256) m = fmaxf(m, kb[i]);  // c = t&31 fixed
  __shared__ float sm[256];
  sm[t] = m;
  __syncthreads();
  if (t < 32) {
    float mm = sm[t];
#pragma unroll
    for (int r = 1; r < 8; ++r) mm = fmaxf(mm, sm[t + r * 32]);
    part[(bh * 8 + chunk) * 32 + t] = mm;
  }
}

// -------- ktv[b,h,kc,vc] = sum_n softmax(k)[n,kc] * v[n,vc] ----------------
__global__ __launch_bounds__(256) void ktv_kernel(
    const float* __restrict__ k, const float* __restrict__ v,
    const float* __restrict__ maxpart, float* __restrict__ ktv) {
  const int bh = blockIdx.x;
  const float* kb = k + (size_t)bh * 131072;
  const float* vb = v + (size_t)bh * 131072;
  __shared__ __align__(16) float ks[8][32];
  __shared__ __align__(16) float vs[8][32];
  __shared__ float cms[32];
  const int t = threadIdx.x;
  if (t < 32) {
    float m = maxpart[bh * 256 + t];
#pragma unroll
    for (int i = 1; i < 8; ++i) m = fmaxf(m, maxpart[bh * 256 + i * 32 + t]);
    cms[t] = m;
  }
  __syncthreads();
  const int kc = t >> 3;         // 0..31
  const int vg = (t & 7) * 4;    // 0,4,...,28
  const float cm = cms[kc];
  float a0 = 0.f, a1 = 0.f, a2 = 0.f, a3 = 0.f, se = 0.f;
  for (int n0 = 0; n0 < 4096; n0 += 8) {
    __syncthreads();
    ks[t >> 5][t & 31] = kb[(size_t)n0 * 32 + t];
    vs[t >> 5][t & 31] = vb[(size_t)n0 * 32 + t];
    __syncthreads();
#pragma unroll
    for (int r = 0; r < 8; ++r) {
      const float e = __expf(ks[r][kc] - cm);
      se += e;  // all 8 threads sharing kc accumulate the identical full sum
      const float4 vv = *reinterpret_cast<const float4*>(&vs[r][vg]);
      a0 = fmaf(e, vv.x, a0); a1 = fmaf(e, vv.y, a1);
      a2 = fmaf(e, vv.z, a2); a3 = fmaf(e, vv.w, a3);
    }
  }
  const float inv = 1.0f / se;
  float* o = ktv + (size_t)bh * 1024 + kc * 32 + vg;
  o[0] = a0 * inv; o[1] = a1 * inv; o[2] = a2 * inv; o[3] = a3 * inv;
}

// ------------------- CRPE depthwise conv (3/5/7 by head group) -------------
template <int K>
__device__ inline float dwconv_tap(const float* __restrict__ base, int y, int x,
                                   const float* __restrict__ wc) {
  constexpr int P = K / 2;
  float a = 0.f;
#pragma unroll
  for (int ky = 0; ky < K; ++ky) {
    const int iy = y + ky - P;
    if (iy < 0 || iy >= 64) continue;
#pragma unroll
    for (int kx = 0; kx < K; ++kx) {
      const int ix = x + kx - P;
      if (ix < 0 || ix >= 64) continue;
      a = fmaf(base[(size_t)(iy * 64 + ix) * 32], wc[ky * K + kx], a);
    }
  }
  return a;
}

__global__ __launch_bounds__(256) void crpe_conv_kernel(
    const float* __restrict__ v, const float* __restrict__ w3,
    const float* __restrict__ b3, const float* __restrict__ w5,
    const float* __restrict__ b5, const float* __restrict__ w7,
    const float* __restrict__ b7, float* __restrict__ convv) {
  const int b = blockIdx.z, h = blockIdx.y;
  const int t = threadIdx.x;
  const int c = t & 31;
  const int p = blockIdx.x * 8 + (t >> 5);  // pixel 0..4095
  const int y = p >> 6, x = p & 63;
  const int ch = h * 32 + c;
  const float* base = v + ((size_t)(b * 8 + h) * 4096) * 32 + c;
  float r;
  if (h < 2)
    r = dwconv_tap<3>(base, y, x, w3 + ch * 9) + b3[ch];
  else if (h < 5)
    r = dwconv_tap<5>(base, y, x, w5 + (ch - 64) * 25) + b5[ch - 64];
  else
    r = dwconv_tap<7>(base, y, x, w7 + (ch - 160) * 49) + b7[ch - 160];
  convv[((size_t)(b * 8 + h) * 4096 + p) * 32 + c] = r;
}

// ------ fa = SCALE*q@ktv + q*conv_v ; write fa + per-block pooled partial --
__global__ __launch_bounds__(256) void factor_att_kernel(
    const float* __restrict__ q, const float* __restrict__ convv,
    const float* __restrict__ ktv, float* __restrict__ fa,
    float* __restrict__ partial) {
  const int b = blockIdx.z, h = blockIdx.y;
  const int n0 = blockIdx.x * 64;
  __shared__ __align__(16) float kt[32][32];
  __shared__ float qs[8][32];
  __shared__ float ps[8][32];
  const int t = threadIdx.x;
#pragma unroll
  for (int i = 0; i < 4; ++i) {
    const int idx = t + i * 256;
    kt[idx >> 5][idx & 31] = ktv[(size_t)(b * 8 + h) * 1024 + idx];
  }
  const size_t off = ((size_t)(b * 8 + h) * 4096 + n0) * 32;
  const float* qb = q + off;
  const float* cb = convv + off;
  float* fb = fa + off;
  const int c = t & 31, rs = t >> 5;
  float pool = 0.f;
  for (int i = 0; i < 8; ++i) {
    __syncthreads();
    qs[rs][c] = qb[i * 256 + t];
    __syncthreads();
    float s = 0.f;
#pragma unroll
    for (int kc = 0; kc < 32; ++kc) s = fmaf(qs[rs][kc], kt[kc][c], s);
    const float val = kScale * s + qs[rs][c] * cb[i * 256 + t];
    fb[i * 256 + t] = val;
    pool += val;
  }
  __syncthreads();
  ps[rs][c] = pool;
  __syncthreads();
  if (t < 32) {
    float s = 0.f;
#pragma unroll
    for (int r = 0; r < 8; ++r) s += ps[r][t];
    partial[((size_t)(b * 8 + h) * 64 + blockIdx.x) * 32 + t] = s;
  }
}

// ------------------ SE MLP -> gfac[b][h] = 1 + sigmoid(...) ----------------
__global__ __launch_bounds__(256) void se_kernel(
    const float* __restrict__ partial, const float* __restrict__ w1,
    const float* __restrict__ w2, float* __restrict__ gfac) {
  const int b = blockIdx.x, t = threadIdx.x;
  __shared__ float pm[256];
  __shared__ float hid[128];
  {
    const int h = t >> 5, c = t & 31;
    const float* p = partial + ((size_t)(b * 8 + h) * 64) * 32 + c;
    float s = 0.f;
#pragma unroll 8
    for (int nc = 0; nc < 64; ++nc) s += p[nc * 32];
    pm[t] = s * (1.0f / 4096.0f);
  }
  __syncthreads();
  if (t < 128) {
    float s = 0.f;
    for (int ch = 0; ch < 256; ++ch) s = fmaf(pm[ch], w1[t * 256 + ch], s);
    hid[t] = fmaxf(s, 0.f);
  }
  __syncthreads();
  if (t < 8) {
    float g = 0.f;
    for (int j = 0; j < 128; ++j) g = fmaf(hid[j], w2[t * 128 + j], g);
    gfac[b * 8 + t] = 1.0f + 1.0f / (1.0f + __expf(-g));
  }
}

// ------- proj GEMM: out[r][j] = sum_ch fa'[r][ch]*pw[j][ch] + pb[j] --------
// fa'[r][ch] = fa[b, ch/32, n, ch%32] * gfac[b][ch/32]
__global__ __launch_bounds__(256) void proj_gemm_kernel(
    const float* __restrict__ fa, const float* __restrict__ gfac,
    const float* __restrict__ w, const float* __restrict__ bias,
    float* __restrict__ out) {
  __shared__ __align__(16) float As[32][68];
  __shared__ __align__(16) float Bs[32][68];
  const int tid = threadIdx.x;
  const int row0 = blockIdx.y * 64;
  const int col0 = blockIdx.x * 64;
  const int tx = tid & 15, ty = tid >> 4;
  const int b = row0 >> 12;  // 64 | 4096 so tile never straddles batches
  float acc[4][4] = {};
  for (int k0 = 0; k0 < 256; k0 += 32) {
#pragma unroll
    for (int i = 0; i < 2; ++i) {
      const int s = tid + i * 256;
      const int r = s >> 3, k4 = s & 7;
      const int ch = k0 + k4 * 4;
      const int hh = ch >> 5, cc = ch & 31;
      const int n = (row0 & 4095) + r;
      const float g = gfac[b * 8 + hh];
      const float4 a4 = *reinterpret_cast<const float4*>(
          &fa[((size_t)(b * 8 + hh) * 4096 + n) * 32 + cc]);
      As[k4 * 4 + 0][r] = a4.x * g; As[k4 * 4 + 1][r] = a4.y * g;
      As[k4 * 4 + 2][r] = a4.z * g; As[k4 * 4 + 3][r] = a4.w * g;
      const float4 b4 = *reinterpret_cast<const float4*>(
          &w[(size_t)(col0 + r) * 256 + k0 + k4 * 4]);
      Bs[k4 * 4 + 0][r] = b4.x; Bs[k4 * 4 + 1][r] = b4.y;
      Bs[k4 * 4 + 2][r] = b4.z; Bs[k4 * 4 + 3][r] = b4.w;
    }
    __syncthreads();
#pragma unroll
    for (int p = 0; p < 32; ++p) {
      const float4 av = *reinterpret_cast<const float4*>(&As[p][ty * 4]);
      const float4 bv = *reinterpret_cast<const float4*>(&Bs[p][tx * 4]);
      const float aa[4] = {av.x, av.y, av.z, av.w};
      const float bb[4] = {bv.x, bv.y, bv.z, bv.w};
#pragma unroll
      for (int i = 0; i < 4; ++i)
#pragma unroll
        for (int j = 0; j < 4; ++j) acc[i][j] = fmaf(aa[i], bb[j], acc[i][j]);
    }
    __syncthreads();
  }
  const int col = col0 + tx * 4;
  const float4 bias4 = *reinterpret_cast<const float4*>(&bias[col]);
#pragma unroll
  for (int i = 0; i < 4; ++i) {
    const int r = row0 + ty * 4 + i;
    float4 o;
    o.x = acc[i][0] + bias4.x; o.y = acc[i][1] + bias4.y;
    o.z = acc[i][2] + bias4.z; o.w = acc[i][3] + bias4.w;
    *reinterpret_cast<float4*>(&out[(size_t)r * 256 + col]) = o;
  }
}

}  // namespace

extern "C" void kernel_launch(void* const* d_in, const int* in_sizes, int n_in,
                              void* d_out, int out_size, void* d_ws,
                              size_t ws_size, hipStream_t stream) {
  const float* x      = (const float*)d_in[0];
  const float* qkv_w  = (const float*)d_in[1];
  const float* qkv_b  = (const float*)d_in[2];
  const float* proj_w = (const float*)d_in[3];
  const float* proj_b = (const float*)d_in[4];
  const float* se_w1  = (const float*)d_in[5];
  const float* se_w2  = (const float*)d_in[6];
  const float* w3 = (const float*)d_in[7];
  const float* b3 = (const float*)d_in[8];
  const float* w5 = (const float*)d_in[9];
  const float* b5 = (const float*)d_in[10];
  const float* w7 = (const float*)d_in[11];
  const float* b7 = (const float*)d_in[12];
  float* out = (float*)d_out;
  float* ws = (float*)d_ws;

  const size_t SZ = (size_t)8 * 8 * 4096 * 32;  // 8388608 floats per tensor
  float* q       = ws;                //  q            [B,h,N,Ch]
  float* kbuf    = ws + SZ;           //  k  -> conv_v after ktv
  float* vbuf    = ws + 2 * SZ;       //  v  -> fa after conv
  float* ktv     = ws + 3 * SZ;       //  64*1024
  float* kmaxp   = ktv + 65536;       //  512*32
  float* partial = kmaxp + 16384;     //  4096*32
  float* gfac    = partial + 131072;  //  64
  (void)ws_size; (void)in_sizes; (void)n_in; (void)out_size;

  qkv_gemm_kernel<<<dim3(12, 512), 256, 0, stream>>>(x, qkv_w, qkv_b, q, kbuf,
                                                     vbuf);
  kmax_kernel<<<dim3(64, 8), 256, 0, stream>>>(kbuf, kmaxp);
  ktv_kernel<<<64, 256, 0, stream>>>(kbuf, vbuf, kmaxp, ktv);
  crpe_conv_kernel<<<dim3(512, 8, 8), 256, 0, stream>>>(vbuf, w3, b3, w5, b5,
                                                        w7, b7, kbuf);
  factor_att_kernel<<<dim3(64, 8, 8), 256, 0, stream>>>(q, kbuf, ktv, vbuf,
                                                        partial);
  se_kernel<<<8, 256, 0, stream>>>(partial, se_w1, se_w2, gfac);
  proj_gemm_kernel<<<dim3(4, 512), 256, 0, stream>>>(vbuf, gfac, proj_w,
                                                     proj_b, out);
}

// Round 2
// 560.350 us; speedup vs baseline: 1.4202x; 1.4202x over previous
//
#include <hip/hip_runtime.h>

namespace {

constexpr float kScale = 0.17677669529663687f;  // 32^-0.5

// ---------------- qkv GEMM: C[r][j] = sum_k x[r][k]*w[j][k] + b[j] ----------
// M=32768, N=768, K=256. 64x64 tile, BK=32, 4x4 micro-tile.
__global__ __launch_bounds__(256) void qkv_gemm_kernel(
    const float* __restrict__ x, const float* __restrict__ w,
    const float* __restrict__ bias, float* __restrict__ q,
    float* __restrict__ kk, float* __restrict__ v) {
  __shared__ __align__(16) float As[32][68];
  __shared__ __align__(16) float Bs[32][68];
  const int tid = threadIdx.x;
  const int row0 = blockIdx.y * 64;
  const int col0 = blockIdx.x * 64;
  const int tx = tid & 15, ty = tid >> 4;
  float acc[4][4] = {};
  for (int k0 = 0; k0 < 256; k0 += 32) {
#pragma unroll
    for (int i = 0; i < 2; ++i) {
      const int s = tid + i * 256;
      const int r = s >> 3, k4 = s & 7;
      const float4 a4 = *reinterpret_cast<const float4*>(
          &x[(size_t)(row0 + r) * 256 + k0 + k4 * 4]);
      As[k4 * 4 + 0][r] = a4.x; As[k4 * 4 + 1][r] = a4.y;
      As[k4 * 4 + 2][r] = a4.z; As[k4 * 4 + 3][r] = a4.w;
      const float4 b4 = *reinterpret_cast<const float4*>(
          &w[(size_t)(col0 + r) * 256 + k0 + k4 * 4]);
      Bs[k4 * 4 + 0][r] = b4.x; Bs[k4 * 4 + 1][r] = b4.y;
      Bs[k4 * 4 + 2][r] = b4.z; Bs[k4 * 4 + 3][r] = b4.w;
    }
    __syncthreads();
#pragma unroll
    for (int p = 0; p < 32; ++p) {
      const float4 av = *reinterpret_cast<const float4*>(&As[p][ty * 4]);
      const float4 bv = *reinterpret_cast<const float4*>(&Bs[p][tx * 4]);
      const float aa[4] = {av.x, av.y, av.z, av.w};
      const float bb[4] = {bv.x, bv.y, bv.z, bv.w};
#pragma unroll
      for (int i = 0; i < 4; ++i)
#pragma unroll
        for (int j = 0; j < 4; ++j) acc[i][j] = fmaf(aa[i], bb[j], acc[i][j]);
    }
    __syncthreads();
  }
  // epilogue: col -> (t, h, c); scatter to q/k/v [b][h][n][c]
  const int col = col0 + tx * 4;
  const int tsel = col >> 8;
  const int hh = (col >> 5) & 7;
  const int cc = col & 31;
  float* dst = (tsel == 0) ? q : (tsel == 1) ? kk : v;
  const float4 bias4 = *reinterpret_cast<const float4*>(&bias[col]);
#pragma unroll
  for (int i = 0; i < 4; ++i) {
    const int r = row0 + ty * 4 + i;
    const int bb_ = r >> 12, n = r & 4095;
    float4 o;
    o.x = acc[i][0] + bias4.x; o.y = acc[i][1] + bias4.y;
    o.z = acc[i][2] + bias4.z; o.w = acc[i][3] + bias4.w;
    *reinterpret_cast<float4*>(
        &dst[((size_t)(bb_ * 8 + hh) * 4096 + n) * 32 + cc]) = o;
  }
}

// -------------- k column-max partials (softmax over N per (b,h,c)) ---------
__global__ __launch_bounds__(256) void kmax_kernel(const float* __restrict__ k,
                                                   float* __restrict__ part) {
  const int bh = blockIdx.x;     // 0..63
  const int chunk = blockIdx.y;  // 0..7 (512 rows each)
  const int t = threadIdx.x;
  const float* kb = k + (size_t)bh * 131072 + (size_t)chunk * 512 * 32;
  float m = -3.4e38f;
  for (int i = t; i < 512 * 32; i += 256) m = fmaxf(m, kb[i]);  // c = t&31 fixed
  __shared__ float sm[256];
  sm[t] = m;
  __syncthreads();
  if (t < 32) {
    float mm = sm[t];
#pragma unroll
    for (int r = 1; r < 8; ++r) mm = fmaxf(mm, sm[t + r * 32]);
    part[(bh * 8 + chunk) * 32 + t] = mm;
  }
}

// ---- ktv partials: pev[bh,chunk,kc,vc] = sum_{n in chunk} e(k)*v ;
//      pe[bh,chunk,kc]  = sum_{n in chunk} e(k)  --------------------------
__global__ __launch_bounds__(256) void ktv_partial_kernel(
    const float* __restrict__ k, const float* __restrict__ v,
    const float* __restrict__ maxpart, float* __restrict__ pev,
    float* __restrict__ pe) {
  const int bh = blockIdx.x;     // 0..63
  const int chunk = blockIdx.y;  // 0..15 (256 rows each)
  const float* kb = k + (size_t)bh * 131072 + (size_t)chunk * 256 * 32;
  const float* vb = v + (size_t)bh * 131072 + (size_t)chunk * 256 * 32;
  __shared__ __align__(16) float ks[32][32];
  __shared__ __align__(16) float vs[32][32];
  __shared__ float cms[32];
  const int t = threadIdx.x;
  if (t < 32) {
    float m = maxpart[bh * 256 + t];
#pragma unroll
    for (int i = 1; i < 8; ++i) m = fmaxf(m, maxpart[bh * 256 + i * 32 + t]);
    cms[t] = m;
  }
  __syncthreads();
  const int kc = t >> 3;       // 0..31
  const int vg = (t & 7) * 4;  // 0,4,...,28
  const float cm = cms[kc];
  const int sr = t >> 3, sc = (t & 7) * 4;  // staging coords (float4)
  float a0 = 0.f, a1 = 0.f, a2 = 0.f, a3 = 0.f, se = 0.f;
  for (int n0 = 0; n0 < 256; n0 += 32) {
    __syncthreads();
    const float4 k4 =
        *reinterpret_cast<const float4*>(&kb[(size_t)(n0 + sr) * 32 + sc]);
    const float4 v4 =
        *reinterpret_cast<const float4*>(&vb[(size_t)(n0 + sr) * 32 + sc]);
    *reinterpret_cast<float4*>(&ks[sr][sc]) = k4;
    *reinterpret_cast<float4*>(&vs[sr][sc]) = v4;
    __syncthreads();
#pragma unroll
    for (int r = 0; r < 32; ++r) {
      const float e = __expf(ks[r][kc] - cm);
      se += e;  // 8 threads sharing kc accumulate identical sums
      const float4 vv = *reinterpret_cast<const float4*>(&vs[r][vg]);
      a0 = fmaf(e, vv.x, a0); a1 = fmaf(e, vv.y, a1);
      a2 = fmaf(e, vv.z, a2); a3 = fmaf(e, vv.w, a3);
    }
  }
  float* o = pev + ((size_t)(bh * 16 + chunk)) * 1024 + kc * 32 + vg;
  o[0] = a0; o[1] = a1; o[2] = a2; o[3] = a3;
  if ((t & 7) == 0) pe[(bh * 16 + chunk) * 32 + kc] = se;
}

// ---- ktv reduce: ktv[bh,kc,vc] = sum_ch pev / sum_ch pe -------------------
__global__ __launch_bounds__(256) void ktv_reduce_kernel(
    const float* __restrict__ pev, const float* __restrict__ pe,
    float* __restrict__ ktv) {
  const int bh = blockIdx.x;
  const int t = threadIdx.x;
  const int kc = t >> 3, vg = (t & 7) * 4;
  float a0 = 0.f, a1 = 0.f, a2 = 0.f, a3 = 0.f, se = 0.f;
  for (int ch = 0; ch < 16; ++ch) {
    const float4 p4 = *reinterpret_cast<const float4*>(
        &pev[((size_t)(bh * 16 + ch)) * 1024 + kc * 32 + vg]);
    a0 += p4.x; a1 += p4.y; a2 += p4.z; a3 += p4.w;
    se += pe[(bh * 16 + ch) * 32 + kc];
  }
  const float inv = 1.0f / se;
  float* o = ktv + (size_t)bh * 1024 + kc * 32 + vg;
  o[0] = a0 * inv; o[1] = a1 * inv; o[2] = a2 * inv; o[3] = a3 * inv;
}

// ------------------- CRPE depthwise conv (3/5/7 by head group) -------------
template <int K>
__device__ inline float dwconv_tap(const float* __restrict__ base, int y, int x,
                                   const float* __restrict__ wc) {
  constexpr int P = K / 2;
  float a = 0.f;
#pragma unroll
  for (int ky = 0; ky < K; ++ky) {
    const int iy = y + ky - P;
    if (iy < 0 || iy >= 64) continue;
#pragma unroll
    for (int kx = 0; kx < K; ++kx) {
      const int ix = x + kx - P;
      if (ix < 0 || ix >= 64) continue;
      a = fmaf(base[(size_t)(iy * 64 + ix) * 32], wc[ky * K + kx], a);
    }
  }
  return a;
}

__global__ __launch_bounds__(256) void crpe_conv_kernel(
    const float* __restrict__ v, const float* __restrict__ w3,
    const float* __restrict__ b3, const float* __restrict__ w5,
    const float* __restrict__ b5, const float* __restrict__ w7,
    const float* __restrict__ b7, float* __restrict__ convv) {
  const int b = blockIdx.z, h = blockIdx.y;
  const int t = threadIdx.x;
  const int c = t & 31;
  const int p = blockIdx.x * 8 + (t >> 5);  // pixel 0..4095
  const int y = p >> 6, x = p & 63;
  const int ch = h * 32 + c;
  const float* base = v + ((size_t)(b * 8 + h) * 4096) * 32 + c;
  float r;
  if (h < 2)
    r = dwconv_tap<3>(base, y, x, w3 + ch * 9) + b3[ch];
  else if (h < 5)
    r = dwconv_tap<5>(base, y, x, w5 + (ch - 64) * 25) + b5[ch - 64];
  else
    r = dwconv_tap<7>(base, y, x, w7 + (ch - 160) * 49) + b7[ch - 160];
  convv[((size_t)(b * 8 + h) * 4096 + p) * 32 + c] = r;
}

// ------ fa = SCALE*q@ktv + q*conv_v ; write fa + per-block pooled partial --
__global__ __launch_bounds__(256) void factor_att_kernel(
    const float* __restrict__ q, const float* __restrict__ convv,
    const float* __restrict__ ktv, float* __restrict__ fa,
    float* __restrict__ partial) {
  const int b = blockIdx.z, h = blockIdx.y;
  const int n0 = blockIdx.x * 64;
  __shared__ __align__(16) float kt[32][32];
  __shared__ float qs[8][32];
  __shared__ float ps[8][32];
  const int t = threadIdx.x;
#pragma unroll
  for (int i = 0; i < 4; ++i) {
    const int idx = t + i * 256;
    kt[idx >> 5][idx & 31] = ktv[(size_t)(b * 8 + h) * 1024 + idx];
  }
  const size_t off = ((size_t)(b * 8 + h) * 4096 + n0) * 32;
  const float* qb = q + off;
  const float* cb = convv + off;
  float* fb = fa + off;
  const int c = t & 31, rs = t >> 5;
  float pool = 0.f;
  for (int i = 0; i < 8; ++i) {
    __syncthreads();
    qs[rs][c] = qb[i * 256 + t];
    __syncthreads();
    float s = 0.f;
#pragma unroll
    for (int kc = 0; kc < 32; ++kc) s = fmaf(qs[rs][kc], kt[kc][c], s);
    const float val = kScale * s + qs[rs][c] * cb[i * 256 + t];
    fb[i * 256 + t] = val;
    pool += val;
  }
  __syncthreads();
  ps[rs][c] = pool;
  __syncthreads();
  if (t < 32) {
    float s = 0.f;
#pragma unroll
    for (int r = 0; r < 8; ++r) s += ps[r][t];
    partial[((size_t)(b * 8 + h) * 64 + blockIdx.x) * 32 + t] = s;
  }
}

// ------------------ SE MLP -> gfac[b][h] = 1 + sigmoid(...) ----------------
__global__ __launch_bounds__(256) void se_kernel(
    const float* __restrict__ partial, const float* __restrict__ w1,
    const float* __restrict__ w2, float* __restrict__ gfac) {
  const int b = blockIdx.x, t = threadIdx.x;
  __shared__ float pm[256];
  __shared__ float hid[128];
  {
    const int h = t >> 5, c = t & 31;
    const float* p = partial + ((size_t)(b * 8 + h) * 64) * 32 + c;
    float s = 0.f;
#pragma unroll 8
    for (int nc = 0; nc < 64; ++nc) s += p[nc * 32];
    pm[t] = s * (1.0f / 4096.0f);
  }
  __syncthreads();
  if (t < 128) {
    float s = 0.f;
    for (int ch = 0; ch < 256; ++ch) s = fmaf(pm[ch], w1[t * 256 + ch], s);
    hid[t] = fmaxf(s, 0.f);
  }
  __syncthreads();
  if (t < 8) {
    float g = 0.f;
    for (int j = 0; j < 128; ++j) g = fmaf(hid[j], w2[t * 128 + j], g);
    gfac[b * 8 + t] = 1.0f + 1.0f / (1.0f + __expf(-g));
  }
}

// ------- proj GEMM: out[r][j] = sum_ch fa'[r][ch]*pw[j][ch] + pb[j] --------
// fa'[r][ch] = fa[b, ch/32, n, ch%32] * gfac[b][ch/32]
__global__ __launch_bounds__(256) void proj_gemm_kernel(
    const float* __restrict__ fa, const float* __restrict__ gfac,
    const float* __restrict__ w, const float* __restrict__ bias,
    float* __restrict__ out) {
  __shared__ __align__(16) float As[32][68];
  __shared__ __align__(16) float Bs[32][68];
  const int tid = threadIdx.x;
  const int row0 = blockIdx.y * 64;
  const int col0 = blockIdx.x * 64;
  const int tx = tid & 15, ty = tid >> 4;
  const int b = row0 >> 12;  // 64 | 4096 so tile never straddles batches
  float acc[4][4] = {};
  for (int k0 = 0; k0 < 256; k0 += 32) {
#pragma unroll
    for (int i = 0; i < 2; ++i) {
      const int s = tid + i * 256;
      const int r = s >> 3, k4 = s & 7;
      const int ch = k0 + k4 * 4;
      const int hh = ch >> 5, cc = ch & 31;
      const int n = (row0 & 4095) + r;
      const float g = gfac[b * 8 + hh];
      const float4 a4 = *reinterpret_cast<const float4*>(
          &fa[((size_t)(b * 8 + hh) * 4096 + n) * 32 + cc]);
      As[k4 * 4 + 0][r] = a4.x * g; As[k4 * 4 + 1][r] = a4.y * g;
      As[k4 * 4 + 2][r] = a4.z * g; As[k4 * 4 + 3][r] = a4.w * g;
      const float4 b4 = *reinterpret_cast<const float4*>(
          &w[(size_t)(col0 + r) * 256 + k0 + k4 * 4]);
      Bs[k4 * 4 + 0][r] = b4.x; Bs[k4 * 4 + 1][r] = b4.y;
      Bs[k4 * 4 + 2][r] = b4.z; Bs[k4 * 4 + 3][r] = b4.w;
    }
    __syncthreads();
#pragma unroll
    for (int p = 0; p < 32; ++p) {
      const float4 av = *reinterpret_cast<const float4*>(&As[p][ty * 4]);
      const float4 bv = *reinterpret_cast<const float4*>(&Bs[p][tx * 4]);
      const float aa[4] = {av.x, av.y, av.z, av.w};
      const float bb[4] = {bv.x, bv.y, bv.z, bv.w};
#pragma unroll
      for (int i = 0; i < 4; ++i)
#pragma unroll
        for (int j = 0; j < 4; ++j) acc[i][j] = fmaf(aa[i], bb[j], acc[i][j]);
    }
    __syncthreads();
  }
  const int col = col0 + tx * 4;
  const float4 bias4 = *reinterpret_cast<const float4*>(&bias[col]);
#pragma unroll
  for (int i = 0; i < 4; ++i) {
    const int r = row0 + ty * 4 + i;
    float4 o;
    o.x = acc[i][0] + bias4.x; o.y = acc[i][1] + bias4.y;
    o.z = acc[i][2] + bias4.z; o.w = acc[i][3] + bias4.w;
    *reinterpret_cast<float4*>(&out[(size_t)r * 256 + col]) = o;
  }
}

}  // namespace

extern "C" void kernel_launch(void* const* d_in, const int* in_sizes, int n_in,
                              void* d_out, int out_size, void* d_ws,
                              size_t ws_size, hipStream_t stream) {
  const float* x      = (const float*)d_in[0];
  const float* qkv_w  = (const float*)d_in[1];
  const float* qkv_b  = (const float*)d_in[2];
  const float* proj_w = (const float*)d_in[3];
  const float* proj_b = (const float*)d_in[4];
  const float* se_w1  = (const float*)d_in[5];
  const float* se_w2  = (const float*)d_in[6];
  const float* w3 = (const float*)d_in[7];
  const float* b3 = (const float*)d_in[8];
  const float* w5 = (const float*)d_in[9];
  const float* b5 = (const float*)d_in[10];
  const float* w7 = (const float*)d_in[11];
  const float* b7 = (const float*)d_in[12];
  float* out = (float*)d_out;
  float* ws = (float*)d_ws;

  const size_t SZ = (size_t)8 * 8 * 4096 * 32;  // 8388608 floats per tensor
  float* q       = ws;                //  q            [B,h,N,Ch]
  float* kbuf    = ws + SZ;           //  k  -> conv_v after ktv
  float* vbuf    = ws + 2 * SZ;       //  v  -> fa after conv
  float* ktv     = ws + 3 * SZ;       //  64*1024
  float* kmaxp   = ktv + 65536;       //  512*32
  float* partial = kmaxp + 16384;     //  4096*32
  float* gfac    = partial + 131072;  //  64
  // ktv partials scratch lives in d_out (1.08M floats << 8.39M); proj_gemm
  // overwrites every element of d_out at the end, so this is safe.
  float* pev = out;                   //  64*16*1024
  float* pe  = out + 64 * 16 * 1024;  //  64*16*32
  (void)ws_size; (void)in_sizes; (void)n_in; (void)out_size;

  qkv_gemm_kernel<<<dim3(12, 512), 256, 0, stream>>>(x, qkv_w, qkv_b, q, kbuf,
                                                     vbuf);
  kmax_kernel<<<dim3(64, 8), 256, 0, stream>>>(kbuf, kmaxp);
  ktv_partial_kernel<<<dim3(64, 16), 256, 0, stream>>>(kbuf, vbuf, kmaxp, pev,
                                                       pe);
  ktv_reduce_kernel<<<64, 256, 0, stream>>>(pev, pe, ktv);
  crpe_conv_kernel<<<dim3(512, 8, 8), 256, 0, stream>>>(vbuf, w3, b3, w5, b5,
                                                        w7, b7, kbuf);
  factor_att_kernel<<<dim3(64, 8, 8), 256, 0, stream>>>(q, kbuf, ktv, vbuf,
                                                        partial);
  se_kernel<<<8, 256, 0, stream>>>(partial, se_w1, se_w2, gfac);
  proj_gemm_kernel<<<dim3(4, 512), 256, 0, stream>>>(vbuf, gfac, proj_w,
                                                     proj_b, out);
}

// Round 3
// 340.701 us; speedup vs baseline: 2.3359x; 1.6447x over previous
//
#include <hip/hip_runtime.h>

namespace {

constexpr float kScale = 0.17677669529663687f;  // 32^-0.5

// ---------------- qkv GEMM: C[r][j] = sum_k x[r][k]*w[j][k] + b[j] ----------
// M=32768, N=768, K=256. 64x64 tile, BK=32, 4x4 micro-tile.
__global__ __launch_bounds__(256) void qkv_gemm_kernel(
    const float* __restrict__ x, const float* __restrict__ w,
    const float* __restrict__ bias, float* __restrict__ q,
    float* __restrict__ kk, float* __restrict__ v) {
  __shared__ __align__(16) float As[32][68];
  __shared__ __align__(16) float Bs[32][68];
  const int tid = threadIdx.x;
  const int row0 = blockIdx.y * 64;
  const int col0 = blockIdx.x * 64;
  const int tx = tid & 15, ty = tid >> 4;
  float acc[4][4] = {};
  for (int k0 = 0; k0 < 256; k0 += 32) {
#pragma unroll
    for (int i = 0; i < 2; ++i) {
      const int s = tid + i * 256;
      const int r = s >> 3, k4 = s & 7;
      const float4 a4 = *reinterpret_cast<const float4*>(
          &x[(size_t)(row0 + r) * 256 + k0 + k4 * 4]);
      As[k4 * 4 + 0][r] = a4.x; As[k4 * 4 + 1][r] = a4.y;
      As[k4 * 4 + 2][r] = a4.z; As[k4 * 4 + 3][r] = a4.w;
      const float4 b4 = *reinterpret_cast<const float4*>(
          &w[(size_t)(col0 + r) * 256 + k0 + k4 * 4]);
      Bs[k4 * 4 + 0][r] = b4.x; Bs[k4 * 4 + 1][r] = b4.y;
      Bs[k4 * 4 + 2][r] = b4.z; Bs[k4 * 4 + 3][r] = b4.w;
    }
    __syncthreads();
#pragma unroll
    for (int p = 0; p < 32; ++p) {
      const float4 av = *reinterpret_cast<const float4*>(&As[p][ty * 4]);
      const float4 bv = *reinterpret_cast<const float4*>(&Bs[p][tx * 4]);
      const float aa[4] = {av.x, av.y, av.z, av.w};
      const float bb[4] = {bv.x, bv.y, bv.z, bv.w};
#pragma unroll
      for (int i = 0; i < 4; ++i)
#pragma unroll
        for (int j = 0; j < 4; ++j) acc[i][j] = fmaf(aa[i], bb[j], acc[i][j]);
    }
    __syncthreads();
  }
  // epilogue: col -> (t, h, c); scatter to q/k/v [b][h][n][c]
  const int col = col0 + tx * 4;
  const int tsel = col >> 8;
  const int hh = (col >> 5) & 7;
  const int cc = col & 31;
  float* dst = (tsel == 0) ? q : (tsel == 1) ? kk : v;
  const float4 bias4 = *reinterpret_cast<const float4*>(&bias[col]);
#pragma unroll
  for (int i = 0; i < 4; ++i) {
    const int r = row0 + ty * 4 + i;
    const int bb_ = r >> 12, n = r & 4095;
    float4 o;
    o.x = acc[i][0] + bias4.x; o.y = acc[i][1] + bias4.y;
    o.z = acc[i][2] + bias4.z; o.w = acc[i][3] + bias4.w;
    *reinterpret_cast<float4*>(
        &dst[((size_t)(bb_ * 8 + hh) * 4096 + n) * 32 + cc]) = o;
  }
}

// -------------- k column-max partials (softmax over N per (b,h,c)) ---------
__global__ __launch_bounds__(256) void kmax_kernel(const float* __restrict__ k,
                                                   float* __restrict__ part) {
  const int bh = blockIdx.x;     // 0..63
  const int chunk = blockIdx.y;  // 0..7 (512 rows each)
  const int t = threadIdx.x;
  const float* kb = k + (size_t)bh * 131072 + (size_t)chunk * 512 * 32;
  float m = -3.4e38f;
  for (int i = t; i < 512 * 32; i += 256) m = fmaxf(m, kb[i]);  // c = t&31 fixed
  __shared__ float sm[256];
  sm[t] = m;
  __syncthreads();
  if (t < 32) {
    float mm = sm[t];
#pragma unroll
    for (int r = 1; r < 8; ++r) mm = fmaxf(mm, sm[t + r * 32]);
    part[(bh * 8 + chunk) * 32 + t] = mm;
  }
}

// ---- ktv partials: pev[bh,chunk,kc,vc] = sum_{n in chunk} e(k)*v ;
//      pe[bh,chunk,kc]  = sum_{n in chunk} e(k)  --------------------------
__global__ __launch_bounds__(256) void ktv_partial_kernel(
    const float* __restrict__ k, const float* __restrict__ v,
    const float* __restrict__ maxpart, float* __restrict__ pev,
    float* __restrict__ pe) {
  const int bh = blockIdx.x;     // 0..63
  const int chunk = blockIdx.y;  // 0..15 (256 rows each)
  const float* kb = k + (size_t)bh * 131072 + (size_t)chunk * 256 * 32;
  const float* vb = v + (size_t)bh * 131072 + (size_t)chunk * 256 * 32;
  __shared__ __align__(16) float ks[32][32];
  __shared__ __align__(16) float vs[32][32];
  __shared__ float cms[32];
  const int t = threadIdx.x;
  if (t < 32) {
    float m = maxpart[bh * 256 + t];
#pragma unroll
    for (int i = 1; i < 8; ++i) m = fmaxf(m, maxpart[bh * 256 + i * 32 + t]);
    cms[t] = m;
  }
  __syncthreads();
  const int kc = t >> 3;       // 0..31
  const int vg = (t & 7) * 4;  // 0,4,...,28
  const float cm = cms[kc];
  const int sr = t >> 3, sc = (t & 7) * 4;  // staging coords (float4)
  float a0 = 0.f, a1 = 0.f, a2 = 0.f, a3 = 0.f, se = 0.f;
  for (int n0 = 0; n0 < 256; n0 += 32) {
    __syncthreads();
    const float4 k4 =
        *reinterpret_cast<const float4*>(&kb[(size_t)(n0 + sr) * 32 + sc]);
    const float4 v4 =
        *reinterpret_cast<const float4*>(&vb[(size_t)(n0 + sr) * 32 + sc]);
    *reinterpret_cast<float4*>(&ks[sr][sc]) = k4;
    *reinterpret_cast<float4*>(&vs[sr][sc]) = v4;
    __syncthreads();
#pragma unroll
    for (int r = 0; r < 32; ++r) {
      const float e = __expf(ks[r][kc] - cm);
      se += e;  // 8 threads sharing kc accumulate identical sums
      const float4 vv = *reinterpret_cast<const float4*>(&vs[r][vg]);
      a0 = fmaf(e, vv.x, a0); a1 = fmaf(e, vv.y, a1);
      a2 = fmaf(e, vv.z, a2); a3 = fmaf(e, vv.w, a3);
    }
  }
  float* o = pev + ((size_t)(bh * 16 + chunk)) * 1024 + kc * 32 + vg;
  o[0] = a0; o[1] = a1; o[2] = a2; o[3] = a3;
  if ((t & 7) == 0) pe[(bh * 16 + chunk) * 32 + kc] = se;
}

// ---- ktv reduce: ktv[bh,kc,vc] = sum_ch pev / sum_ch pe -------------------
__global__ __launch_bounds__(256) void ktv_reduce_kernel(
    const float* __restrict__ pev, const float* __restrict__ pe,
    float* __restrict__ ktv) {
  const int bh = blockIdx.x;
  const int t = threadIdx.x;
  const int kc = t >> 3, vg = (t & 7) * 4;
  float a0 = 0.f, a1 = 0.f, a2 = 0.f, a3 = 0.f, se = 0.f;
  for (int ch = 0; ch < 16; ++ch) {
    const float4 p4 = *reinterpret_cast<const float4*>(
        &pev[((size_t)(bh * 16 + ch)) * 1024 + kc * 32 + vg]);
    a0 += p4.x; a1 += p4.y; a2 += p4.z; a3 += p4.w;
    se += pe[(bh * 16 + ch) * 32 + kc];
  }
  const float inv = 1.0f / se;
  float* o = ktv + (size_t)bh * 1024 + kc * 32 + vg;
  o[0] = a0 * inv; o[1] = a1 * inv; o[2] = a2 * inv; o[3] = a3 * inv;
}

// ------------------- CRPE depthwise conv (3/5/7 by head group) -------------
// One block per (b, h, 4-row strip). Stage 10 image rows (zero-padded) in
// LDS via contiguous float4 loads; each thread owns (c, 8-wide x group) and
// slides a register window so each LDS read feeds up to K FMAs.
template <int K>
__device__ __forceinline__ void crpe_tile(const float (*lds)[64][32],
                                          const float* __restrict__ wch,
                                          float bias, int c, int x0,
                                          float* __restrict__ outbase) {
  constexpr int P = K / 2;
  constexpr int W = 8 + K - 1;
  float wreg[K * K];
#pragma unroll
  for (int i = 0; i < K * K; ++i) wreg[i] = wch[i];
#pragma unroll
  for (int yy = 0; yy < 4; ++yy) {
    float acc[8];
#pragma unroll
    for (int i = 0; i < 8; ++i) acc[i] = bias;
#pragma unroll
    for (int ky = 0; ky < K; ++ky) {
      const int lrow = yy + ky + (3 - P);
      float win[W];
#pragma unroll
      for (int j = 0; j < W; ++j) {
        const int xx = x0 + j - P;
        const int xc = min(max(xx, 0), 63);
        const float val = lds[lrow][xc][c];
        win[j] = (xx == xc) ? val : 0.f;
      }
#pragma unroll
      for (int kx = 0; kx < K; ++kx) {
        const float wgt = wreg[ky * K + kx];
#pragma unroll
        for (int i = 0; i < 8; ++i) acc[i] = fmaf(win[i + kx], wgt, acc[i]);
      }
    }
#pragma unroll
    for (int i = 0; i < 8; ++i)
      outbase[(size_t)(yy * 64 + x0 + i) * 32 + c] = acc[i];
  }
}

__global__ __launch_bounds__(256) void crpe_conv_kernel(
    const float* __restrict__ v, const float* __restrict__ w3,
    const float* __restrict__ b3, const float* __restrict__ w5,
    const float* __restrict__ b5, const float* __restrict__ w7,
    const float* __restrict__ b7, float* __restrict__ convv) {
  __shared__ __align__(16) float lds[10][64][32];  // 80 KB
  const int t = threadIdx.x;
  const int y0 = blockIdx.x * 4;
  const int h = blockIdx.y, b = blockIdx.z;
  const float* vb = v + (size_t)(b * 8 + h) * 131072;
  // stage rows y0-3 .. y0+6, zero-filled outside [0,64)
  const int ytop = y0 - 3;
  float4* lds4 = reinterpret_cast<float4*>(&lds[0][0][0]);
#pragma unroll
  for (int i = 0; i < 20; ++i) {
    const int idx = t + i * 256;  // float4 index, 512 per row
    const int row = idx >> 9;
    const int y = ytop + row;
    float4 val = {0.f, 0.f, 0.f, 0.f};
    if (y >= 0 && y < 64)
      val = *reinterpret_cast<const float4*>(
          &vb[(size_t)y * 2048 + (size_t)(idx & 511) * 4]);
    lds4[idx] = val;
  }
  __syncthreads();
  const int c = t & 31;
  const int x0 = (t >> 5) * 8;
  const int ch = h * 32 + c;
  float* outbase = convv + ((size_t)(b * 8 + h) * 4096 + y0 * 64) * 32;
  if (h < 2)
    crpe_tile<3>(lds, w3 + ch * 9, b3[ch], c, x0, outbase);
  else if (h < 5)
    crpe_tile<5>(lds, w5 + (ch - 64) * 25, b5[ch - 64], c, x0, outbase);
  else
    crpe_tile<7>(lds, w7 + (ch - 160) * 49, b7[ch - 160], c, x0, outbase);
}

// ------ fa = SCALE*q@ktv + q*conv_v ; write fa + per-block pooled partial --
__global__ __launch_bounds__(256) void factor_att_kernel(
    const float* __restrict__ q, const float* __restrict__ convv,
    const float* __restrict__ ktv, float* __restrict__ fa,
    float* __restrict__ partial) {
  const int b = blockIdx.z, h = blockIdx.y;
  const int n0 = blockIdx.x * 64;
  __shared__ __align__(16) float kt[32][32];
  __shared__ float qs[8][32];
  __shared__ float ps[8][32];
  const int t = threadIdx.x;
#pragma unroll
  for (int i = 0; i < 4; ++i) {
    const int idx = t + i * 256;
    kt[idx >> 5][idx & 31] = ktv[(size_t)(b * 8 + h) * 1024 + idx];
  }
  const size_t off = ((size_t)(b * 8 + h) * 4096 + n0) * 32;
  const float* qb = q + off;
  const float* cb = convv + off;
  float* fb = fa + off;
  const int c = t & 31, rs = t >> 5;
  float pool = 0.f;
  for (int i = 0; i < 8; ++i) {
    __syncthreads();
    qs[rs][c] = qb[i * 256 + t];
    __syncthreads();
    float s = 0.f;
#pragma unroll
    for (int kc = 0; kc < 32; ++kc) s = fmaf(qs[rs][kc], kt[kc][c], s);
    const float val = kScale * s + qs[rs][c] * cb[i * 256 + t];
    fb[i * 256 + t] = val;
    pool += val;
  }
  __syncthreads();
  ps[rs][c] = pool;
  __syncthreads();
  if (t < 32) {
    float s = 0.f;
#pragma unroll
    for (int r = 0; r < 8; ++r) s += ps[r][t];
    partial[((size_t)(b * 8 + h) * 64 + blockIdx.x) * 32 + t] = s;
  }
}

// ------------------ SE MLP -> gfac[b][h] = 1 + sigmoid(...) ----------------
__global__ __launch_bounds__(256) void se_kernel(
    const float* __restrict__ partial, const float* __restrict__ w1,
    const float* __restrict__ w2, float* __restrict__ gfac) {
  const int b = blockIdx.x, t = threadIdx.x;
  __shared__ float pm[256];
  __shared__ float hid[128];
  {
    const int h = t >> 5, c = t & 31;
    const float* p = partial + ((size_t)(b * 8 + h) * 64) * 32 + c;
    float s = 0.f;
#pragma unroll 8
    for (int nc = 0; nc < 64; ++nc) s += p[nc * 32];
    pm[t] = s * (1.0f / 4096.0f);
  }
  __syncthreads();
  if (t < 128) {
    float s = 0.f;
    for (int ch = 0; ch < 256; ++ch) s = fmaf(pm[ch], w1[t * 256 + ch], s);
    hid[t] = fmaxf(s, 0.f);
  }
  __syncthreads();
  if (t < 8) {
    float g = 0.f;
    for (int j = 0; j < 128; ++j) g = fmaf(hid[j], w2[t * 128 + j], g);
    gfac[b * 8 + t] = 1.0f + 1.0f / (1.0f + __expf(-g));
  }
}

// ------- proj GEMM: out[r][j] = sum_ch fa'[r][ch]*pw[j][ch] + pb[j] --------
// fa'[r][ch] = fa[b, ch/32, n, ch%32] * gfac[b][ch/32]
__global__ __launch_bounds__(256) void proj_gemm_kernel(
    const float* __restrict__ fa, const float* __restrict__ gfac,
    const float* __restrict__ w, const float* __restrict__ bias,
    float* __restrict__ out) {
  __shared__ __align__(16) float As[32][68];
  __shared__ __align__(16) float Bs[32][68];
  const int tid = threadIdx.x;
  const int row0 = blockIdx.y * 64;
  const int col0 = blockIdx.x * 64;
  const int tx = tid & 15, ty = tid >> 4;
  const int b = row0 >> 12;  // 64 | 4096 so tile never straddles batches
  float acc[4][4] = {};
  for (int k0 = 0; k0 < 256; k0 += 32) {
#pragma unroll
    for (int i = 0; i < 2; ++i) {
      const int s = tid + i * 256;
      const int r = s >> 3, k4 = s & 7;
      const int ch = k0 + k4 * 4;
      const int hh = ch >> 5, cc = ch & 31;
      const int n = (row0 & 4095) + r;
      const float g = gfac[b * 8 + hh];
      const float4 a4 = *reinterpret_cast<const float4*>(
          &fa[((size_t)(b * 8 + hh) * 4096 + n) * 32 + cc]);
      As[k4 * 4 + 0][r] = a4.x * g; As[k4 * 4 + 1][r] = a4.y * g;
      As[k4 * 4 + 2][r] = a4.z * g; As[k4 * 4 + 3][r] = a4.w * g;
      const float4 b4 = *reinterpret_cast<const float4*>(
          &w[(size_t)(col0 + r) * 256 + k0 + k4 * 4]);
      Bs[k4 * 4 + 0][r] = b4.x; Bs[k4 * 4 + 1][r] = b4.y;
      Bs[k4 * 4 + 2][r] = b4.z; Bs[k4 * 4 + 3][r] = b4.w;
    }
    __syncthreads();
#pragma unroll
    for (int p = 0; p < 32; ++p) {
      const float4 av = *reinterpret_cast<const float4*>(&As[p][ty * 4]);
      const float4 bv = *reinterpret_cast<const float4*>(&Bs[p][tx * 4]);
      const float aa[4] = {av.x, av.y, av.z, av.w};
      const float bb[4] = {bv.x, bv.y, bv.z, bv.w};
#pragma unroll
      for (int i = 0; i < 4; ++i)
#pragma unroll
        for (int j = 0; j < 4; ++j) acc[i][j] = fmaf(aa[i], bb[j], acc[i][j]);
    }
    __syncthreads();
  }
  const int col = col0 + tx * 4;
  const float4 bias4 = *reinterpret_cast<const float4*>(&bias[col]);
#pragma unroll
  for (int i = 0; i < 4; ++i) {
    const int r = row0 + ty * 4 + i;
    float4 o;
    o.x = acc[i][0] + bias4.x; o.y = acc[i][1] + bias4.y;
    o.z = acc[i][2] + bias4.z; o.w = acc[i][3] + bias4.w;
    *reinterpret_cast<float4*>(&out[(size_t)r * 256 + col]) = o;
  }
}

}  // namespace

extern "C" void kernel_launch(void* const* d_in, const int* in_sizes, int n_in,
                              void* d_out, int out_size, void* d_ws,
                              size_t ws_size, hipStream_t stream) {
  const float* x      = (const float*)d_in[0];
  const float* qkv_w  = (const float*)d_in[1];
  const float* qkv_b  = (const float*)d_in[2];
  const float* proj_w = (const float*)d_in[3];
  const float* proj_b = (const float*)d_in[4];
  const float* se_w1  = (const float*)d_in[5];
  const float* se_w2  = (const float*)d_in[6];
  const float* w3 = (const float*)d_in[7];
  const float* b3 = (const float*)d_in[8];
  const float* w5 = (const float*)d_in[9];
  const float* b5 = (const float*)d_in[10];
  const float* w7 = (const float*)d_in[11];
  const float* b7 = (const float*)d_in[12];
  float* out = (float*)d_out;
  float* ws = (float*)d_ws;

  const size_t SZ = (size_t)8 * 8 * 4096 * 32;  // 8388608 floats per tensor
  float* q       = ws;                //  q            [B,h,N,Ch]
  float* kbuf    = ws + SZ;           //  k  -> conv_v after ktv
  float* vbuf    = ws + 2 * SZ;       //  v  -> fa after conv
  float* ktv     = ws + 3 * SZ;       //  64*1024
  float* kmaxp   = ktv + 65536;       //  512*32
  float* partial = kmaxp + 16384;     //  4096*32
  float* gfac    = partial + 131072;  //  64
  // ktv partials scratch lives in d_out (1.08M floats << 8.39M); proj_gemm
  // overwrites every element of d_out at the end, so this is safe.
  float* pev = out;                   //  64*16*1024
  float* pe  = out + 64 * 16 * 1024;  //  64*16*32
  (void)ws_size; (void)in_sizes; (void)n_in; (void)out_size;

  qkv_gemm_kernel<<<dim3(12, 512), 256, 0, stream>>>(x, qkv_w, qkv_b, q, kbuf,
                                                     vbuf);
  kmax_kernel<<<dim3(64, 8), 256, 0, stream>>>(kbuf, kmaxp);
  ktv_partial_kernel<<<dim3(64, 16), 256, 0, stream>>>(kbuf, vbuf, kmaxp, pev,
                                                       pe);
  ktv_reduce_kernel<<<64, 256, 0, stream>>>(pev, pe, ktv);
  crpe_conv_kernel<<<dim3(16, 8, 8), 256, 0, stream>>>(vbuf, w3, b3, w5, b5,
                                                       w7, b7, kbuf);
  factor_att_kernel<<<dim3(64, 8, 8), 256, 0, stream>>>(q, kbuf, ktv, vbuf,
                                                        partial);
  se_kernel<<<8, 256, 0, stream>>>(partial, se_w1, se_w2, gfac);
  proj_gemm_kernel<<<dim3(4, 512), 256, 0, stream>>>(vbuf, gfac, proj_w,
                                                     proj_b, out);
}

// Round 4
// 320.830 us; speedup vs baseline: 2.4805x; 1.0619x over previous
//
#include <hip/hip_runtime.h>

namespace {

constexpr float kScale = 0.17677669529663687f;  // 32^-0.5

// ---------------- qkv GEMM: C[r][j] = sum_k x[r][k]*w[j][k] + b[j] ----------
// M=32768, N=768, K=256. 128x128 tile, BK=16, 8x8 micro-tile (2x2 of 4x4).
// LDS stride 132: write conflicts 2-way (free), b128 reads 16B-aligned.
__global__ __launch_bounds__(256, 4) void qkv_gemm_kernel(
    const float* __restrict__ x, const float* __restrict__ w,
    const float* __restrict__ bias, float* __restrict__ q,
    float* __restrict__ kk, float* __restrict__ v) {
  __shared__ __align__(16) float As[16][132];
  __shared__ __align__(16) float Bs[16][132];
  const int tid = threadIdx.x;
  const int row0 = blockIdx.y * 128;
  const int col0 = blockIdx.x * 128;
  const int tx = tid & 15, ty = tid >> 4;
  float acc[2][2][4][4] = {};
  for (int k0 = 0; k0 < 256; k0 += 16) {
    float4 a[2], b[2];
#pragma unroll
    for (int i = 0; i < 2; ++i) {
      const int f = tid + i * 256;
      const int r = f >> 2, kq = f & 3;
      a[i] = *reinterpret_cast<const float4*>(
          &x[(size_t)(row0 + r) * 256 + k0 + kq * 4]);
      b[i] = *reinterpret_cast<const float4*>(
          &w[(size_t)(col0 + r) * 256 + k0 + kq * 4]);
    }
    __syncthreads();
#pragma unroll
    for (int i = 0; i < 2; ++i) {
      const int f = tid + i * 256;
      const int r = f >> 2, kq = f & 3;
      As[kq * 4 + 0][r] = a[i].x; As[kq * 4 + 1][r] = a[i].y;
      As[kq * 4 + 2][r] = a[i].z; As[kq * 4 + 3][r] = a[i].w;
      Bs[kq * 4 + 0][r] = b[i].x; Bs[kq * 4 + 1][r] = b[i].y;
      Bs[kq * 4 + 2][r] = b[i].z; Bs[kq * 4 + 3][r] = b[i].w;
    }
    __syncthreads();
#pragma unroll
    for (int p = 0; p < 16; ++p) {
      const float4 a0 = *reinterpret_cast<const float4*>(&As[p][ty * 4]);
      const float4 a1 = *reinterpret_cast<const float4*>(&As[p][64 + ty * 4]);
      const float4 b0 = *reinterpret_cast<const float4*>(&Bs[p][tx * 4]);
      const float4 b1 = *reinterpret_cast<const float4*>(&Bs[p][64 + tx * 4]);
      const float av[2][4] = {{a0.x, a0.y, a0.z, a0.w},
                              {a1.x, a1.y, a1.z, a1.w}};
      const float bv[2][4] = {{b0.x, b0.y, b0.z, b0.w},
                              {b1.x, b1.y, b1.z, b1.w}};
#pragma unroll
      for (int rh = 0; rh < 2; ++rh)
#pragma unroll
        for (int ch = 0; ch < 2; ++ch)
#pragma unroll
          for (int i = 0; i < 4; ++i)
#pragma unroll
            for (int j = 0; j < 4; ++j)
              acc[rh][ch][i][j] =
                  fmaf(av[rh][i], bv[ch][j], acc[rh][ch][i][j]);
    }
  }
  // epilogue: col -> (t, h, c); scatter to q/k/v [b][h][n][c]
#pragma unroll
  for (int rh = 0; rh < 2; ++rh) {
#pragma unroll
    for (int i = 0; i < 4; ++i) {
      const int r = row0 + rh * 64 + ty * 4 + i;
      const int bb_ = r >> 12, n = r & 4095;
#pragma unroll
      for (int chh = 0; chh < 2; ++chh) {
        const int col = col0 + chh * 64 + tx * 4;
        const int tsel = col >> 8;
        const int hh = (col >> 5) & 7;
        const int cc = col & 31;
        float* dst = (tsel == 0) ? q : (tsel == 1) ? kk : v;
        const float4 bias4 = *reinterpret_cast<const float4*>(&bias[col]);
        float4 o;
        o.x = acc[rh][chh][i][0] + bias4.x;
        o.y = acc[rh][chh][i][1] + bias4.y;
        o.z = acc[rh][chh][i][2] + bias4.z;
        o.w = acc[rh][chh][i][3] + bias4.w;
        *reinterpret_cast<float4*>(
            &dst[((size_t)(bb_ * 8 + hh) * 4096 + n) * 32 + cc]) = o;
      }
    }
  }
}

// -------------- k column-max partials (softmax over N per (b,h,c)) ---------
__global__ __launch_bounds__(256) void kmax_kernel(const float* __restrict__ k,
                                                   float* __restrict__ part) {
  const int bh = blockIdx.x;     // 0..63
  const int chunk = blockIdx.y;  // 0..7 (512 rows each)
  const int t = threadIdx.x;
  const float* kb = k + (size_t)bh * 131072 + (size_t)chunk * 512 * 32;
  float m = -3.4e38f;
  for (int i = t; i < 512 * 32; i += 256) m = fmaxf(m, kb[i]);  // c = t&31 fixed
  __shared__ float sm[256];
  sm[t] = m;
  __syncthreads();
  if (t < 32) {
    float mm = sm[t];
#pragma unroll
    for (int r = 1; r < 8; ++r) mm = fmaxf(mm, sm[t + r * 32]);
    part[(bh * 8 + chunk) * 32 + t] = mm;
  }
}

// ---- ktv partials: pev[bh,chunk,kc,vc] = sum_{n in chunk} e(k)*v ;
//      pe[bh,chunk,kc]  = sum_{n in chunk} e(k)  --------------------------
__global__ __launch_bounds__(256) void ktv_partial_kernel(
    const float* __restrict__ k, const float* __restrict__ v,
    const float* __restrict__ maxpart, float* __restrict__ pev,
    float* __restrict__ pe) {
  const int bh = blockIdx.x;     // 0..63
  const int chunk = blockIdx.y;  // 0..15 (256 rows each)
  const float* kb = k + (size_t)bh * 131072 + (size_t)chunk * 256 * 32;
  const float* vb = v + (size_t)bh * 131072 + (size_t)chunk * 256 * 32;
  __shared__ __align__(16) float ks[32][32];
  __shared__ __align__(16) float vs[32][32];
  __shared__ float cms[32];
  const int t = threadIdx.x;
  if (t < 32) {
    float m = maxpart[bh * 256 + t];
#pragma unroll
    for (int i = 1; i < 8; ++i) m = fmaxf(m, maxpart[bh * 256 + i * 32 + t]);
    cms[t] = m;
  }
  __syncthreads();
  const int kc = t >> 3;       // 0..31
  const int vg = (t & 7) * 4;  // 0,4,...,28
  const float cm = cms[kc];
  const int sr = t >> 3, sc = (t & 7) * 4;  // staging coords (float4)
  float a0 = 0.f, a1 = 0.f, a2 = 0.f, a3 = 0.f, se = 0.f;
  for (int n0 = 0; n0 < 256; n0 += 32) {
    __syncthreads();
    const float4 k4 =
        *reinterpret_cast<const float4*>(&kb[(size_t)(n0 + sr) * 32 + sc]);
    const float4 v4 =
        *reinterpret_cast<const float4*>(&vb[(size_t)(n0 + sr) * 32 + sc]);
    *reinterpret_cast<float4*>(&ks[sr][sc]) = k4;
    *reinterpret_cast<float4*>(&vs[sr][sc]) = v4;
    __syncthreads();
#pragma unroll
    for (int r = 0; r < 32; ++r) {
      const float e = __expf(ks[r][kc] - cm);
      se += e;  // 8 threads sharing kc accumulate identical sums
      const float4 vv = *reinterpret_cast<const float4*>(&vs[r][vg]);
      a0 = fmaf(e, vv.x, a0); a1 = fmaf(e, vv.y, a1);
      a2 = fmaf(e, vv.z, a2); a3 = fmaf(e, vv.w, a3);
    }
  }
  float* o = pev + ((size_t)(bh * 16 + chunk)) * 1024 + kc * 32 + vg;
  o[0] = a0; o[1] = a1; o[2] = a2; o[3] = a3;
  if ((t & 7) == 0) pe[(bh * 16 + chunk) * 32 + kc] = se;
}

// ---- ktv reduce: ktv[bh,kc,vc] = sum_ch pev / sum_ch pe -------------------
__global__ __launch_bounds__(256) void ktv_reduce_kernel(
    const float* __restrict__ pev, const float* __restrict__ pe,
    float* __restrict__ ktv) {
  const int bh = blockIdx.x;
  const int t = threadIdx.x;
  const int kc = t >> 3, vg = (t & 7) * 4;
  float a0 = 0.f, a1 = 0.f, a2 = 0.f, a3 = 0.f, se = 0.f;
  for (int ch = 0; ch < 16; ++ch) {
    const float4 p4 = *reinterpret_cast<const float4*>(
        &pev[((size_t)(bh * 16 + ch)) * 1024 + kc * 32 + vg]);
    a0 += p4.x; a1 += p4.y; a2 += p4.z; a3 += p4.w;
    se += pe[(bh * 16 + ch) * 32 + kc];
  }
  const float inv = 1.0f / se;
  float* o = ktv + (size_t)bh * 1024 + kc * 32 + vg;
  o[0] = a0 * inv; o[1] = a1 * inv; o[2] = a2 * inv; o[3] = a3 * inv;
}

// ------------------- CRPE depthwise conv (3/5/7 by head group) -------------
// One block per (b, h, 4-row strip). Stage 10 image rows (zero-padded) in
// LDS via contiguous float4 loads; each thread owns (c, 8-wide x group) and
// slides a register window so each LDS read feeds up to K FMAs.
template <int K>
__device__ __forceinline__ void crpe_tile(const float (*lds)[64][32],
                                          const float* __restrict__ wch,
                                          float bias, int c, int x0,
                                          float* __restrict__ outbase) {
  constexpr int P = K / 2;
  constexpr int W = 8 + K - 1;
  float wreg[K * K];
#pragma unroll
  for (int i = 0; i < K * K; ++i) wreg[i] = wch[i];
#pragma unroll
  for (int yy = 0; yy < 4; ++yy) {
    float acc[8];
#pragma unroll
    for (int i = 0; i < 8; ++i) acc[i] = bias;
#pragma unroll
    for (int ky = 0; ky < K; ++ky) {
      const int lrow = yy + ky + (3 - P);
      float win[W];
#pragma unroll
      for (int j = 0; j < W; ++j) {
        const int xx = x0 + j - P;
        const int xc = min(max(xx, 0), 63);
        const float val = lds[lrow][xc][c];
        win[j] = (xx == xc) ? val : 0.f;
      }
#pragma unroll
      for (int kx = 0; kx < K; ++kx) {
        const float wgt = wreg[ky * K + kx];
#pragma unroll
        for (int i = 0; i < 8; ++i) acc[i] = fmaf(win[i + kx], wgt, acc[i]);
      }
    }
#pragma unroll
    for (int i = 0; i < 8; ++i)
      outbase[(size_t)(yy * 64 + x0 + i) * 32 + c] = acc[i];
  }
}

__global__ __launch_bounds__(256) void crpe_conv_kernel(
    const float* __restrict__ v, const float* __restrict__ w3,
    const float* __restrict__ b3, const float* __restrict__ w5,
    const float* __restrict__ b5, const float* __restrict__ w7,
    const float* __restrict__ b7, float* __restrict__ convv) {
  __shared__ __align__(16) float lds[10][64][32];  // 80 KB
  const int t = threadIdx.x;
  const int y0 = blockIdx.x * 4;
  const int h = blockIdx.y, b = blockIdx.z;
  const float* vb = v + (size_t)(b * 8 + h) * 131072;
  // stage rows y0-3 .. y0+6, zero-filled outside [0,64)
  const int ytop = y0 - 3;
  float4* lds4 = reinterpret_cast<float4*>(&lds[0][0][0]);
#pragma unroll
  for (int i = 0; i < 20; ++i) {
    const int idx = t + i * 256;  // float4 index, 512 per row
    const int row = idx >> 9;
    const int y = ytop + row;
    float4 val = {0.f, 0.f, 0.f, 0.f};
    if (y >= 0 && y < 64)
      val = *reinterpret_cast<const float4*>(
          &vb[(size_t)y * 2048 + (size_t)(idx & 511) * 4]);
    lds4[idx] = val;
  }
  __syncthreads();
  const int c = t & 31;
  const int x0 = (t >> 5) * 8;
  const int ch = h * 32 + c;
  float* outbase = convv + ((size_t)(b * 8 + h) * 4096 + y0 * 64) * 32;
  if (h < 2)
    crpe_tile<3>(lds, w3 + ch * 9, b3[ch], c, x0, outbase);
  else if (h < 5)
    crpe_tile<5>(lds, w5 + (ch - 64) * 25, b5[ch - 64], c, x0, outbase);
  else
    crpe_tile<7>(lds, w7 + (ch - 160) * 49, b7[ch - 160], c, x0, outbase);
}

// ------ fa = SCALE*q@ktv + q*conv_v ; write fa + per-block pooled partial --
__global__ __launch_bounds__(256) void factor_att_kernel(
    const float* __restrict__ q, const float* __restrict__ convv,
    const float* __restrict__ ktv, float* __restrict__ fa,
    float* __restrict__ partial) {
  const int b = blockIdx.z, h = blockIdx.y;
  const int n0 = blockIdx.x * 64;
  __shared__ __align__(16) float kt[32][32];
  __shared__ float qs[8][32];
  __shared__ float ps[8][32];
  const int t = threadIdx.x;
#pragma unroll
  for (int i = 0; i < 4; ++i) {
    const int idx = t + i * 256;
    kt[idx >> 5][idx & 31] = ktv[(size_t)(b * 8 + h) * 1024 + idx];
  }
  const size_t off = ((size_t)(b * 8 + h) * 4096 + n0) * 32;
  const float* qb = q + off;
  const float* cb = convv + off;
  float* fb = fa + off;
  const int c = t & 31, rs = t >> 5;
  float pool = 0.f;
  for (int i = 0; i < 8; ++i) {
    __syncthreads();
    qs[rs][c] = qb[i * 256 + t];
    __syncthreads();
    float s = 0.f;
#pragma unroll
    for (int kc = 0; kc < 32; ++kc) s = fmaf(qs[rs][kc], kt[kc][c], s);
    const float val = kScale * s + qs[rs][c] * cb[i * 256 + t];
    fb[i * 256 + t] = val;
    pool += val;
  }
  __syncthreads();
  ps[rs][c] = pool;
  __syncthreads();
  if (t < 32) {
    float s = 0.f;
#pragma unroll
    for (int r = 0; r < 8; ++r) s += ps[r][t];
    partial[((size_t)(b * 8 + h) * 64 + blockIdx.x) * 32 + t] = s;
  }
}

// ------------------ SE MLP -> gfac[b][h] = 1 + sigmoid(...) ----------------
__global__ __launch_bounds__(256) void se_kernel(
    const float* __restrict__ partial, const float* __restrict__ w1,
    const float* __restrict__ w2, float* __restrict__ gfac) {
  const int b = blockIdx.x, t = threadIdx.x;
  __shared__ float pm[256];
  __shared__ float hid[128];
  {
    const int h = t >> 5, c = t & 31;
    const float* p = partial + ((size_t)(b * 8 + h) * 64) * 32 + c;
    float s = 0.f;
#pragma unroll 8
    for (int nc = 0; nc < 64; ++nc) s += p[nc * 32];
    pm[t] = s * (1.0f / 4096.0f);
  }
  __syncthreads();
  if (t < 128) {
    float s = 0.f;
    for (int ch = 0; ch < 256; ++ch) s = fmaf(pm[ch], w1[t * 256 + ch], s);
    hid[t] = fmaxf(s, 0.f);
  }
  __syncthreads();
  if (t < 8) {
    float g = 0.f;
    for (int j = 0; j < 128; ++j) g = fmaf(hid[j], w2[t * 128 + j], g);
    gfac[b * 8 + t] = 1.0f + 1.0f / (1.0f + __expf(-g));
  }
}

// ------- proj GEMM: out[r][j] = sum_ch fa'[r][ch]*pw[j][ch] + pb[j] --------
// fa'[r][ch] = fa[b, ch/32, n, ch%32] * gfac[b][ch/32]. Same 128x128 tile.
__global__ __launch_bounds__(256, 4) void proj_gemm_kernel(
    const float* __restrict__ fa, const float* __restrict__ gfac,
    const float* __restrict__ w, const float* __restrict__ bias,
    float* __restrict__ out) {
  __shared__ __align__(16) float As[16][132];
  __shared__ __align__(16) float Bs[16][132];
  const int tid = threadIdx.x;
  const int row0 = blockIdx.y * 128;
  const int col0 = blockIdx.x * 128;
  const int tx = tid & 15, ty = tid >> 4;
  const int b = row0 >> 12;  // 128 | 4096 so tile never straddles batches
  float acc[2][2][4][4] = {};
  for (int k0 = 0; k0 < 256; k0 += 16) {
    float4 a[2], b4s[2];
#pragma unroll
    for (int i = 0; i < 2; ++i) {
      const int f = tid + i * 256;
      const int r = f >> 2, kq = f & 3;
      const int chv = k0 + kq * 4;
      const int hh = chv >> 5, cc = chv & 31;
      const int n = (row0 & 4095) + r;
      const float g = gfac[b * 8 + hh];
      float4 a4 = *reinterpret_cast<const float4*>(
          &fa[((size_t)(b * 8 + hh) * 4096 + n) * 32 + cc]);
      a4.x *= g; a4.y *= g; a4.z *= g; a4.w *= g;
      a[i] = a4;
      b4s[i] = *reinterpret_cast<const float4*>(
          &w[(size_t)(col0 + r) * 256 + k0 + kq * 4]);
    }
    __syncthreads();
#pragma unroll
    for (int i = 0; i < 2; ++i) {
      const int f = tid + i * 256;
      const int r = f >> 2, kq = f & 3;
      As[kq * 4 + 0][r] = a[i].x; As[kq * 4 + 1][r] = a[i].y;
      As[kq * 4 + 2][r] = a[i].z; As[kq * 4 + 3][r] = a[i].w;
      Bs[kq * 4 + 0][r] = b4s[i].x; Bs[kq * 4 + 1][r] = b4s[i].y;
      Bs[kq * 4 + 2][r] = b4s[i].z; Bs[kq * 4 + 3][r] = b4s[i].w;
    }
    __syncthreads();
#pragma unroll
    for (int p = 0; p < 16; ++p) {
      const float4 a0 = *reinterpret_cast<const float4*>(&As[p][ty * 4]);
      const float4 a1 = *reinterpret_cast<const float4*>(&As[p][64 + ty * 4]);
      const float4 b0 = *reinterpret_cast<const float4*>(&Bs[p][tx * 4]);
      const float4 b1 = *reinterpret_cast<const float4*>(&Bs[p][64 + tx * 4]);
      const float av[2][4] = {{a0.x, a0.y, a0.z, a0.w},
                              {a1.x, a1.y, a1.z, a1.w}};
      const float bv[2][4] = {{b0.x, b0.y, b0.z, b0.w},
                              {b1.x, b1.y, b1.z, b1.w}};
#pragma unroll
      for (int rh = 0; rh < 2; ++rh)
#pragma unroll
        for (int ch = 0; ch < 2; ++ch)
#pragma unroll
          for (int i = 0; i < 4; ++i)
#pragma unroll
            for (int j = 0; j < 4; ++j)
              acc[rh][ch][i][j] =
                  fmaf(av[rh][i], bv[ch][j], acc[rh][ch][i][j]);
    }
  }
#pragma unroll
  for (int rh = 0; rh < 2; ++rh) {
#pragma unroll
    for (int i = 0; i < 4; ++i) {
      const int r = row0 + rh * 64 + ty * 4 + i;
#pragma unroll
      for (int chh = 0; chh < 2; ++chh) {
        const int col = col0 + chh * 64 + tx * 4;
        const float4 bias4 = *reinterpret_cast<const float4*>(&bias[col]);
        float4 o;
        o.x = acc[rh][chh][i][0] + bias4.x;
        o.y = acc[rh][chh][i][1] + bias4.y;
        o.z = acc[rh][chh][i][2] + bias4.z;
        o.w = acc[rh][chh][i][3] + bias4.w;
        *reinterpret_cast<float4*>(&out[(size_t)r * 256 + col]) = o;
      }
    }
  }
}

}  // namespace

extern "C" void kernel_launch(void* const* d_in, const int* in_sizes, int n_in,
                              void* d_out, int out_size, void* d_ws,
                              size_t ws_size, hipStream_t stream) {
  const float* x      = (const float*)d_in[0];
  const float* qkv_w  = (const float*)d_in[1];
  const float* qkv_b  = (const float*)d_in[2];
  const float* proj_w = (const float*)d_in[3];
  const float* proj_b = (const float*)d_in[4];
  const float* se_w1  = (const float*)d_in[5];
  const float* se_w2  = (const float*)d_in[6];
  const float* w3 = (const float*)d_in[7];
  const float* b3 = (const float*)d_in[8];
  const float* w5 = (const float*)d_in[9];
  const float* b5 = (const float*)d_in[10];
  const float* w7 = (const float*)d_in[11];
  const float* b7 = (const float*)d_in[12];
  float* out = (float*)d_out;
  float* ws = (float*)d_ws;

  const size_t SZ = (size_t)8 * 8 * 4096 * 32;  // 8388608 floats per tensor
  float* q       = ws;                //  q            [B,h,N,Ch]
  float* kbuf    = ws + SZ;           //  k  -> conv_v after ktv
  float* vbuf    = ws + 2 * SZ;       //  v  -> fa after conv
  float* ktv     = ws + 3 * SZ;       //  64*1024
  float* kmaxp   = ktv + 65536;       //  512*32
  float* partial = kmaxp + 16384;     //  4096*32
  float* gfac    = partial + 131072;  //  64
  // ktv partials scratch lives in d_out (1.08M floats << 8.39M); proj_gemm
  // overwrites every element of d_out at the end, so this is safe.
  float* pev = out;                   //  64*16*1024
  float* pe  = out + 64 * 16 * 1024;  //  64*16*32
  (void)ws_size; (void)in_sizes; (void)n_in; (void)out_size;

  qkv_gemm_kernel<<<dim3(6, 256), 256, 0, stream>>>(x, qkv_w, qkv_b, q, kbuf,
                                                    vbuf);
  kmax_kernel<<<dim3(64, 8), 256, 0, stream>>>(kbuf, kmaxp);
  ktv_partial_kernel<<<dim3(64, 16), 256, 0, stream>>>(kbuf, vbuf, kmaxp, pev,
                                                       pe);
  ktv_reduce_kernel<<<64, 256, 0, stream>>>(pev, pe, ktv);
  crpe_conv_kernel<<<dim3(16, 8, 8), 256, 0, stream>>>(vbuf, w3, b3, w5, b5,
                                                       w7, b7, kbuf);
  factor_att_kernel<<<dim3(64, 8, 8), 256, 0, stream>>>(q, kbuf, ktv, vbuf,
                                                        partial);
  se_kernel<<<8, 256, 0, stream>>>(partial, se_w1, se_w2, gfac);
  proj_gemm_kernel<<<dim3(2, 256), 256, 0, stream>>>(vbuf, gfac, proj_w,
                                                     proj_b, out);
}